// Round 1
// baseline (194.759 us; speedup 1.0000x reference)
//
#include <hip/hip_runtime.h>
#include <hip/hip_bf16.h>

// DissipationNetwork: per-row tiny ICNN, N=2^21 rows, D=2, H=4.
// Pure map over rows -> 1 thread = 4 rows, float4 I/O, all math in registers.

#define NROWS_PER_THREAD 4

__device__ __forceinline__ float sp(float v) {
    // softplus(x) = max(x,0) + log1p(exp(-|x|))  (== jax.nn.softplus)
    float e = __expf(-fabsf(v));
    return fmaxf(v, 0.0f) + __logf(1.0f + e);
}

__device__ __forceinline__ float posw(float w) {
    // PositiveLinear reparam, EPS=1: w>=0 -> w + exp(-1); w<0 -> exp(w-1)
    const float EXP_NEG1 = 0.36787944117144233f;
    return (w >= 0.0f) ? (w + EXP_NEG1) : __expf(w - 1.0f);
}

// One middle stage:
//   v[h]  = xs[h] * sp(lin4(xh, w_cpm, b_cpm)[h])
//   u[d]  = x0s[d] * lin4(xh, w_clm, b_clm)[d]
//   xs'   = sp(lin4(xh,w_xl,b_xl) + posw(w_cp)@v + w_cl@u)
//   xh'   = sp(lin4(xh, w_xp, b_xp))
__device__ __forceinline__ void mid_stage(
    float xs[NROWS_PER_THREAD][4], float xh[NROWS_PER_THREAD][4],
    const float XS0[NROWS_PER_THREAD][2],
    const float* __restrict__ w_xl,  const float* __restrict__ b_xl,
    const float* __restrict__ w_cpm, const float* __restrict__ b_cpm,
    const float* __restrict__ w_cp,
    const float* __restrict__ w_clm, const float* __restrict__ b_clm,
    const float* __restrict__ w_cl,
    const float* __restrict__ w_xp,  const float* __restrict__ b_xp)
{
    float v[NROWS_PER_THREAD][4];
    #pragma unroll
    for (int h = 0; h < 4; ++h) {
        float w0 = w_cpm[h*4+0], w1 = w_cpm[h*4+1], w2 = w_cpm[h*4+2], w3 = w_cpm[h*4+3];
        float b  = b_cpm[h];
        #pragma unroll
        for (int r = 0; r < NROWS_PER_THREAD; ++r) {
            float m = sp(fmaf(w0, xh[r][0], fmaf(w1, xh[r][1], fmaf(w2, xh[r][2], fmaf(w3, xh[r][3], b)))));
            v[r][h] = xs[r][h] * m;
        }
    }
    float u[NROWS_PER_THREAD][2];
    #pragma unroll
    for (int d = 0; d < 2; ++d) {
        float w0 = w_clm[d*4+0], w1 = w_clm[d*4+1], w2 = w_clm[d*4+2], w3 = w_clm[d*4+3];
        float b  = b_clm[d];
        #pragma unroll
        for (int r = 0; r < NROWS_PER_THREAD; ++r) {
            float t = fmaf(w0, xh[r][0], fmaf(w1, xh[r][1], fmaf(w2, xh[r][2], fmaf(w3, xh[r][3], b))));
            u[r][d] = XS0[r][d] * t;
        }
    }
    float ns[NROWS_PER_THREAD][4];
    #pragma unroll
    for (int h = 0; h < 4; ++h) {
        float a0 = w_xl[h*4+0], a1 = w_xl[h*4+1], a2 = w_xl[h*4+2], a3 = w_xl[h*4+3];
        float ab = b_xl[h];
        float p0 = posw(w_cp[h*4+0]), p1 = posw(w_cp[h*4+1]);
        float p2 = posw(w_cp[h*4+2]), p3 = posw(w_cp[h*4+3]);
        float c0 = w_cl[h*2+0], c1 = w_cl[h*2+1];
        #pragma unroll
        for (int r = 0; r < NROWS_PER_THREAD; ++r) {
            float t = fmaf(a0, xh[r][0], fmaf(a1, xh[r][1], fmaf(a2, xh[r][2], fmaf(a3, xh[r][3], ab))));
            t = fmaf(p0, v[r][0], fmaf(p1, v[r][1], fmaf(p2, v[r][2], fmaf(p3, v[r][3], t))));
            t = fmaf(c0, u[r][0], fmaf(c1, u[r][1], t));
            ns[r][h] = sp(t);
        }
    }
    float nh[NROWS_PER_THREAD][4];
    #pragma unroll
    for (int h = 0; h < 4; ++h) {
        float w0 = w_xp[h*4+0], w1 = w_xp[h*4+1], w2 = w_xp[h*4+2], w3 = w_xp[h*4+3];
        float b  = b_xp[h];
        #pragma unroll
        for (int r = 0; r < NROWS_PER_THREAD; ++r)
            nh[r][h] = sp(fmaf(w0, xh[r][0], fmaf(w1, xh[r][1], fmaf(w2, xh[r][2], fmaf(w3, xh[r][3], b)))));
    }
    #pragma unroll
    for (int r = 0; r < NROWS_PER_THREAD; ++r)
        #pragma unroll
        for (int h = 0; h < 4; ++h) { xs[r][h] = ns[r][h]; xh[r][h] = nh[r][h]; }
}

__global__ __launch_bounds__(256)
void dissip_kernel(
    const float* __restrict__ x,      const float* __restrict__ xst,
    const float* __restrict__ w_xin,  const float* __restrict__ b_xin,
    const float* __restrict__ w_xp1,  const float* __restrict__ b_xp1,
    const float* __restrict__ w_xp2,  const float* __restrict__ b_xp2,
    const float* __restrict__ w_xl1,  const float* __restrict__ b_xl1,
    const float* __restrict__ w_xl2,  const float* __restrict__ b_xl2,
    const float* __restrict__ w_xl3,  const float* __restrict__ b_xl3,
    const float* __restrict__ w_xlo,  const float* __restrict__ b_xlo,
    const float* __restrict__ w_cp1,  const float* __restrict__ w_cp2,
    const float* __restrict__ w_cpo,
    const float* __restrict__ w_cp1m, const float* __restrict__ b_cp1m,
    const float* __restrict__ w_cp2m, const float* __restrict__ b_cp2m,
    const float* __restrict__ w_cpom, const float* __restrict__ b_cpom,
    const float* __restrict__ w_clin, const float* __restrict__ w_cl1,
    const float* __restrict__ w_cl2,  const float* __restrict__ w_clo,
    const float* __restrict__ w_clinm,const float* __restrict__ b_clinm,
    const float* __restrict__ w_cl1m, const float* __restrict__ b_cl1m,
    const float* __restrict__ w_cl2m, const float* __restrict__ b_cl2m,
    const float* __restrict__ w_clom, const float* __restrict__ b_clom,
    float* __restrict__ out, int n)
{
    const int tid = blockIdx.x * blockDim.x + threadIdx.x;
    const int r0  = tid * NROWS_PER_THREAD;
    if (r0 >= n) return;
    const bool full = (r0 + NROWS_PER_THREAD <= n);

    float X0[NROWS_PER_THREAD][2], XS0[NROWS_PER_THREAD][2];
    if (full) {
        const float4 xa = *(const float4*)(x   + (size_t)r0 * 2);
        const float4 xb = *(const float4*)(x   + (size_t)r0 * 2 + 4);
        const float4 sa = *(const float4*)(xst + (size_t)r0 * 2);
        const float4 sb = *(const float4*)(xst + (size_t)r0 * 2 + 4);
        X0[0][0]=xa.x;  X0[0][1]=xa.y;  X0[1][0]=xa.z;  X0[1][1]=xa.w;
        X0[2][0]=xb.x;  X0[2][1]=xb.y;  X0[3][0]=xb.z;  X0[3][1]=xb.w;
        XS0[0][0]=sa.x; XS0[0][1]=sa.y; XS0[1][0]=sa.z; XS0[1][1]=sa.w;
        XS0[2][0]=sb.x; XS0[2][1]=sb.y; XS0[3][0]=sb.z; XS0[3][1]=sb.w;
    } else {
        #pragma unroll
        for (int r = 0; r < NROWS_PER_THREAD; ++r) {
            int row = r0 + r;
            if (row < n) {
                X0[r][0]  = x[(size_t)row*2];   X0[r][1]  = x[(size_t)row*2+1];
                XS0[r][0] = xst[(size_t)row*2]; XS0[r][1] = xst[(size_t)row*2+1];
            } else {
                X0[r][0] = X0[r][1] = XS0[r][0] = XS0[r][1] = 0.0f;
            }
        }
    }

    float xs[NROWS_PER_THREAD][4], xh[NROWS_PER_THREAD][4];

    // ---- stage 1: xs = sp(lin(x0,w_xl1,b_xl1) + w_clin @ (x0s * (w_clinm@x0+b)))
    float tcl[NROWS_PER_THREAD][2];
    #pragma unroll
    for (int d = 0; d < 2; ++d) {
        float w0 = w_clinm[d*2+0], w1 = w_clinm[d*2+1], b = b_clinm[d];
        #pragma unroll
        for (int r = 0; r < NROWS_PER_THREAD; ++r)
            tcl[r][d] = XS0[r][d] * fmaf(w0, X0[r][0], fmaf(w1, X0[r][1], b));
    }
    #pragma unroll
    for (int h = 0; h < 4; ++h) {
        float wl0 = w_xl1[h*2+0], wl1 = w_xl1[h*2+1], bl = b_xl1[h];
        float wc0 = w_clin[h*2+0], wc1 = w_clin[h*2+1];
        #pragma unroll
        for (int r = 0; r < NROWS_PER_THREAD; ++r) {
            float a = fmaf(wl0, X0[r][0], fmaf(wl1, X0[r][1], bl));
            a = fmaf(wc0, tcl[r][0], fmaf(wc1, tcl[r][1], a));
            xs[r][h] = sp(a);
        }
    }
    // xh = sp(lin(x0, w_xin, b_xin))
    #pragma unroll
    for (int h = 0; h < 4; ++h) {
        float w0 = w_xin[h*2+0], w1 = w_xin[h*2+1], b = b_xin[h];
        #pragma unroll
        for (int r = 0; r < NROWS_PER_THREAD; ++r)
            xh[r][h] = sp(fmaf(w0, X0[r][0], fmaf(w1, X0[r][1], b)));
    }

    // ---- stage 2 & 3
    mid_stage(xs, xh, XS0, w_xl2, b_xl2, w_cp1m, b_cp1m, w_cp1, w_cl1m, b_cl1m, w_cl1, w_xp1, b_xp1);
    mid_stage(xs, xh, XS0, w_xl3, b_xl3, w_cp2m, b_cp2m, w_cp2, w_cl2m, b_cl2m, w_cl2, w_xp2, b_xp2);

    // ---- output stage
    float o[NROWS_PER_THREAD];
    {
        // vv[h] = xs[h] * sp(lin4(xh, w_cpom, b_cpom)[h])
        float vv[NROWS_PER_THREAD][4];
        #pragma unroll
        for (int h = 0; h < 4; ++h) {
            float w0 = w_cpom[h*4+0], w1 = w_cpom[h*4+1], w2 = w_cpom[h*4+2], w3 = w_cpom[h*4+3];
            float b  = b_cpom[h];
            #pragma unroll
            for (int r = 0; r < NROWS_PER_THREAD; ++r) {
                float m = sp(fmaf(w0, xh[r][0], fmaf(w1, xh[r][1], fmaf(w2, xh[r][2], fmaf(w3, xh[r][3], b)))));
                vv[r][h] = xs[r][h] * m;
            }
        }
        // uu[d] = x0s[d] * (lin4(xh, w_clom, b_clom)[d])
        float uu[NROWS_PER_THREAD][2];
        #pragma unroll
        for (int d = 0; d < 2; ++d) {
            float w0 = w_clom[d*4+0], w1 = w_clom[d*4+1], w2 = w_clom[d*4+2], w3 = w_clom[d*4+3];
            float b  = b_clom[d];
            #pragma unroll
            for (int r = 0; r < NROWS_PER_THREAD; ++r) {
                float t = fmaf(w0, xh[r][0], fmaf(w1, xh[r][1], fmaf(w2, xh[r][2], fmaf(w3, xh[r][3], b))));
                uu[r][d] = XS0[r][d] * t;
            }
        }
        float l0 = w_xlo[0], l1 = w_xlo[1], l2 = w_xlo[2], l3 = w_xlo[3], lb = b_xlo[0];
        float p0 = posw(w_cpo[0]), p1 = posw(w_cpo[1]), p2 = posw(w_cpo[2]), p3 = posw(w_cpo[3]);
        float c0 = w_clo[0], c1 = w_clo[1];
        #pragma unroll
        for (int r = 0; r < NROWS_PER_THREAD; ++r) {
            float t = fmaf(l0, xh[r][0], fmaf(l1, xh[r][1], fmaf(l2, xh[r][2], fmaf(l3, xh[r][3], lb))));
            t = fmaf(p0, vv[r][0], fmaf(p1, vv[r][1], fmaf(p2, vv[r][2], fmaf(p3, vv[r][3], t))));
            t = fmaf(c0, uu[r][0], fmaf(c1, uu[r][1], t));
            o[r] = sp(t);
        }
    }

    if (full) {
        *(float4*)(out + r0) = make_float4(o[0], o[1], o[2], o[3]);
    } else {
        #pragma unroll
        for (int r = 0; r < NROWS_PER_THREAD; ++r)
            if (r0 + r < n) out[r0 + r] = o[r];
    }
}

extern "C" void kernel_launch(void* const* d_in, const int* in_sizes, int n_in,
                              void* d_out, int out_size, void* d_ws, size_t ws_size,
                              hipStream_t stream) {
    const float* p[37];
    for (int i = 0; i < 37; ++i) p[i] = (const float*)d_in[i];
    const int n = in_sizes[0] / 2;  // N rows (D=2)
    const int threads = 256;
    const int rows_per_block = threads * NROWS_PER_THREAD;
    const int blocks = (n + rows_per_block - 1) / rows_per_block;

    dissip_kernel<<<dim3(blocks), dim3(threads), 0, stream>>>(
        p[0],  p[1],
        p[2],  p[3],  p[4],  p[5],  p[6],  p[7],
        p[8],  p[9],  p[10], p[11], p[12], p[13],
        p[14], p[15],
        p[16], p[17], p[18],
        p[19], p[20], p[21], p[22], p[23], p[24],
        p[25], p[26], p[27], p[28],
        p[29], p[30], p[31], p[32], p[33], p[34],
        p[35], p[36],
        (float*)d_out, n);
}

// Round 2
// 180.602 us; speedup vs baseline: 1.0784x; 1.0784x over previous
//
#include <hip/hip_runtime.h>

// DissipationNetwork: per-row tiny ICNN, N=2^21 rows, D=2, H=4. VALU-bound map.
// Two kernels:
//  1) prep_kernel: fold PositiveLinear reparam + log2-domain softplus constants
//     into a 267-float transformed weight buffer in d_ws (runs every launch).
//  2) dissip_main: 2 rows/thread, all math in registers, softplus in log2 domain
//     (raw v_exp_f32/v_log_f32, no range-conversion muls).
//
// log2-domain: activation a = ln2 * a_hat, a_hat = sp2(z_hat), z_hat = z*log2e.
// sp2(y) = max(y,0) + log2(1 + 2^-|y|).  Scale factors telescope; absorbed into
// precomputed weights (input-side *log2e, product-path *ln2, output *ln2 once).

#define NR 2
#define L2Ef 1.4426950408889634f
#define LN2f 0.6931471805599453f

__device__ __forceinline__ float sp2(float y) {
    float e = __builtin_amdgcn_exp2f(-fabsf(y));   // 2^-|y|, modifier folds
    float l = __builtin_amdgcn_logf(1.0f + e);     // log2(1+e)
    return fmaxf(y, 0.0f) + l;
}

__device__ __forceinline__ float posw(float w) {
    // PositiveLinear reparam, EPS=1
    return (w >= 0.0f) ? (w + 0.36787944117144233f) : __expf(w - 1.0f);
}

// ---- transformed weight buffer layout (267 floats) ----
// stage1: [0]w_xl1*L2E(8) [8]b_xl1*L2E(4) [12]w_clin*L2E(8) [20]w_clinm(4)
//         [24]b_clinm(2) [26]w_xin*L2E(8) [34]b_xin*L2E(4)
// stage block (base B, 94 floats):
//   B+0  w_cpm (16)      (unscaled)
//   B+16 b_cpm*L2E (4)
//   B+20 w_clm*LN2 (8)
//   B+28 b_clm (2)       (unscaled)
//   B+30 w_xl (16)       (unscaled)
//   B+46 b_xl*L2E (4)
//   B+50 LN2*posw(w_cp) (16)
//   B+66 w_cl*L2E (8)
//   B+74 w_xp (16)       (unscaled)
//   B+90 b_xp*L2E (4)
// stage2 B=38, stage3 B=132
// out: [226]w_cpom(16) [242]b_cpom*L2E(4) [246]w_clom*LN2(8) [254]b_clom(2)
//      [256]w_xlo(4) [260]b_xlo*L2E(1) [261]LN2*posw(w_cpo)(4) [265]w_clo*L2E(2)

__global__ __launch_bounds__(256)
void prep_kernel(
    const float* __restrict__ w_xin,  const float* __restrict__ b_xin,
    const float* __restrict__ w_xp1,  const float* __restrict__ b_xp1,
    const float* __restrict__ w_xp2,  const float* __restrict__ b_xp2,
    const float* __restrict__ w_xl1,  const float* __restrict__ b_xl1,
    const float* __restrict__ w_xl2,  const float* __restrict__ b_xl2,
    const float* __restrict__ w_xl3,  const float* __restrict__ b_xl3,
    const float* __restrict__ w_xlo,  const float* __restrict__ b_xlo,
    const float* __restrict__ w_cp1,  const float* __restrict__ w_cp2,
    const float* __restrict__ w_cpo,
    const float* __restrict__ w_cp1m, const float* __restrict__ b_cp1m,
    const float* __restrict__ w_cp2m, const float* __restrict__ b_cp2m,
    const float* __restrict__ w_cpom, const float* __restrict__ b_cpom,
    const float* __restrict__ w_clin, const float* __restrict__ w_cl1,
    const float* __restrict__ w_cl2,  const float* __restrict__ w_clo,
    const float* __restrict__ w_clinm,const float* __restrict__ b_clinm,
    const float* __restrict__ w_cl1m, const float* __restrict__ b_cl1m,
    const float* __restrict__ w_cl2m, const float* __restrict__ b_cl2m,
    const float* __restrict__ w_clom, const float* __restrict__ b_clom,
    float* __restrict__ wb)
{
    const int t = threadIdx.x;
#define CPY(dst, src, cnt)    if (t < (cnt)) wb[(dst)+t] = src[t];
#define SCL(dst, src, cnt, s) if (t < (cnt)) wb[(dst)+t] = (s) * src[t];
#define PW(dst, src, cnt)     if (t < (cnt)) wb[(dst)+t] = LN2f * posw(src[t]);
    // stage1
    SCL(0,   w_xl1,  8, L2Ef)
    SCL(8,   b_xl1,  4, L2Ef)
    SCL(12,  w_clin, 8, L2Ef)
    CPY(20,  w_clinm,4)
    CPY(24,  b_clinm,2)
    SCL(26,  w_xin,  8, L2Ef)
    SCL(34,  b_xin,  4, L2Ef)
    // stage2 @38
    CPY(38,  w_cp1m,16)
    SCL(54,  b_cp1m, 4, L2Ef)
    SCL(58,  w_cl1m, 8, LN2f)
    CPY(66,  b_cl1m, 2)
    CPY(68,  w_xl2, 16)
    SCL(84,  b_xl2,  4, L2Ef)
    PW (88,  w_cp1, 16)
    SCL(104, w_cl1,  8, L2Ef)
    CPY(112, w_xp1, 16)
    SCL(128, b_xp1,  4, L2Ef)
    // stage3 @132
    CPY(132, w_cp2m,16)
    SCL(148, b_cp2m, 4, L2Ef)
    SCL(152, w_cl2m, 8, LN2f)
    CPY(160, b_cl2m, 2)
    CPY(162, w_xl3, 16)
    SCL(178, b_xl3,  4, L2Ef)
    PW (182, w_cp2, 16)
    SCL(198, w_cl2,  8, L2Ef)
    CPY(206, w_xp2, 16)
    SCL(222, b_xp2,  4, L2Ef)
    // out @226
    CPY(226, w_cpom,16)
    SCL(242, b_cpom, 4, L2Ef)
    SCL(246, w_clom, 8, LN2f)
    CPY(254, b_clom, 2)
    CPY(256, w_xlo,  4)
    SCL(260, b_xlo,  1, L2Ef)
    PW (261, w_cpo,  4)
    SCL(265, w_clo,  2, L2Ef)
#undef CPY
#undef SCL
#undef PW
}

__device__ __forceinline__ void mid_stage(
    const float* __restrict__ wb,   // stage base
    float xs[NR][4], float xh[NR][4], const float XS0[NR][2])
{
    // v_hat[h] = xs[h] * sp2(w_cpm@xh + b_cpm)
    float v[NR][4];
    #pragma unroll
    for (int h = 0; h < 4; ++h) {
        float w0 = wb[h*4+0], w1 = wb[h*4+1], w2 = wb[h*4+2], w3 = wb[h*4+3];
        float b  = wb[16+h];
        #pragma unroll
        for (int r = 0; r < NR; ++r) {
            float m = sp2(fmaf(w0, xh[r][0], fmaf(w1, xh[r][1], fmaf(w2, xh[r][2], fmaf(w3, xh[r][3], b)))));
            v[r][h] = xs[r][h] * m;
        }
    }
    // u[d] = x0s[d] * (w_clm@xh + b_clm)   (natural units)
    float u[NR][2];
    #pragma unroll
    for (int d = 0; d < 2; ++d) {
        float w0 = wb[20+d*4+0], w1 = wb[20+d*4+1], w2 = wb[20+d*4+2], w3 = wb[20+d*4+3];
        float b  = wb[28+d];
        #pragma unroll
        for (int r = 0; r < NR; ++r) {
            float t = fmaf(w0, xh[r][0], fmaf(w1, xh[r][1], fmaf(w2, xh[r][2], fmaf(w3, xh[r][3], b))));
            u[r][d] = XS0[r][d] * t;
        }
    }
    // xs' = sp2(w_xl@xh + b_xl + P@v + w_cl@u);  xh' = sp2(w_xp@xh + b_xp)
    float ns[NR][4], nh[NR][4];
    #pragma unroll
    for (int h = 0; h < 4; ++h) {
        float a0 = wb[30+h*4+0], a1 = wb[30+h*4+1], a2 = wb[30+h*4+2], a3 = wb[30+h*4+3];
        float ab = wb[46+h];
        float p0 = wb[50+h*4+0], p1 = wb[50+h*4+1], p2 = wb[50+h*4+2], p3 = wb[50+h*4+3];
        float c0 = wb[66+h*2+0], c1 = wb[66+h*2+1];
        #pragma unroll
        for (int r = 0; r < NR; ++r) {
            float t = fmaf(a0, xh[r][0], fmaf(a1, xh[r][1], fmaf(a2, xh[r][2], fmaf(a3, xh[r][3], ab))));
            t = fmaf(p0, v[r][0], fmaf(p1, v[r][1], fmaf(p2, v[r][2], fmaf(p3, v[r][3], t))));
            t = fmaf(c0, u[r][0], fmaf(c1, u[r][1], t));
            ns[r][h] = sp2(t);
        }
    }
    #pragma unroll
    for (int h = 0; h < 4; ++h) {
        float w0 = wb[74+h*4+0], w1 = wb[74+h*4+1], w2 = wb[74+h*4+2], w3 = wb[74+h*4+3];
        float b  = wb[90+h];
        #pragma unroll
        for (int r = 0; r < NR; ++r)
            nh[r][h] = sp2(fmaf(w0, xh[r][0], fmaf(w1, xh[r][1], fmaf(w2, xh[r][2], fmaf(w3, xh[r][3], b)))));
    }
    #pragma unroll
    for (int r = 0; r < NR; ++r)
        #pragma unroll
        for (int h = 0; h < 4; ++h) { xs[r][h] = ns[r][h]; xh[r][h] = nh[r][h]; }
}

__global__ __launch_bounds__(256, 4)
void dissip_main(const float* __restrict__ x, const float* __restrict__ xst,
                 const float* __restrict__ wb, float* __restrict__ out, int n)
{
    const int tid = blockIdx.x * blockDim.x + threadIdx.x;
    const int r0  = tid * NR;
    if (r0 >= n) return;
    const bool full = (r0 + NR <= n);

    float X0[NR][2], XS0[NR][2];
    if (full) {
        const float4 xa = *(const float4*)(x   + (size_t)r0 * 2);
        const float4 sa = *(const float4*)(xst + (size_t)r0 * 2);
        X0[0][0]=xa.x;  X0[0][1]=xa.y;  X0[1][0]=xa.z;  X0[1][1]=xa.w;
        XS0[0][0]=sa.x; XS0[0][1]=sa.y; XS0[1][0]=sa.z; XS0[1][1]=sa.w;
    } else {
        #pragma unroll
        for (int r = 0; r < NR; ++r) {
            int row = r0 + r;
            if (row < n) {
                X0[r][0]  = x[(size_t)row*2];   X0[r][1]  = x[(size_t)row*2+1];
                XS0[r][0] = xst[(size_t)row*2]; XS0[r][1] = xst[(size_t)row*2+1];
            } else { X0[r][0]=X0[r][1]=XS0[r][0]=XS0[r][1]=0.0f; }
        }
    }

    float xs[NR][4], xh[NR][4];

    // ---- stage 1 ----
    float tcl[NR][2];
    {
        float m00=wb[20], m01=wb[21], m10=wb[22], m11=wb[23], c0=wb[24], c1=wb[25];
        #pragma unroll
        for (int r = 0; r < NR; ++r) {
            tcl[r][0] = XS0[r][0] * fmaf(m00, X0[r][0], fmaf(m01, X0[r][1], c0));
            tcl[r][1] = XS0[r][1] * fmaf(m10, X0[r][0], fmaf(m11, X0[r][1], c1));
        }
    }
    #pragma unroll
    for (int h = 0; h < 4; ++h) {
        float a0 = wb[h*2+0], a1 = wb[h*2+1], ab = wb[8+h];
        float c0 = wb[12+h*2+0], c1 = wb[12+h*2+1];
        #pragma unroll
        for (int r = 0; r < NR; ++r) {
            float a = fmaf(a0, X0[r][0], fmaf(a1, X0[r][1], ab));
            a = fmaf(c0, tcl[r][0], fmaf(c1, tcl[r][1], a));
            xs[r][h] = sp2(a);
        }
    }
    #pragma unroll
    for (int h = 0; h < 4; ++h) {
        float w0 = wb[26+h*2+0], w1 = wb[26+h*2+1], b = wb[34+h];
        #pragma unroll
        for (int r = 0; r < NR; ++r)
            xh[r][h] = sp2(fmaf(w0, X0[r][0], fmaf(w1, X0[r][1], b)));
    }

    // ---- stages 2, 3 ----
    mid_stage(wb + 38,  xs, xh, XS0);
    mid_stage(wb + 132, xs, xh, XS0);

    // ---- output stage ----
    float o[NR];
    {
        const float* ob = wb + 226;
        float vv[NR][4];
        #pragma unroll
        for (int h = 0; h < 4; ++h) {
            float w0 = ob[h*4+0], w1 = ob[h*4+1], w2 = ob[h*4+2], w3 = ob[h*4+3];
            float b  = ob[16+h];
            #pragma unroll
            for (int r = 0; r < NR; ++r) {
                float m = sp2(fmaf(w0, xh[r][0], fmaf(w1, xh[r][1], fmaf(w2, xh[r][2], fmaf(w3, xh[r][3], b)))));
                vv[r][h] = xs[r][h] * m;
            }
        }
        float uu[NR][2];
        #pragma unroll
        for (int d = 0; d < 2; ++d) {
            float w0 = ob[20+d*4+0], w1 = ob[20+d*4+1], w2 = ob[20+d*4+2], w3 = ob[20+d*4+3];
            float b  = ob[28+d];
            #pragma unroll
            for (int r = 0; r < NR; ++r) {
                float t = fmaf(w0, xh[r][0], fmaf(w1, xh[r][1], fmaf(w2, xh[r][2], fmaf(w3, xh[r][3], b))));
                uu[r][d] = XS0[r][d] * t;
            }
        }
        float l0 = ob[30], l1 = ob[31], l2 = ob[32], l3 = ob[33], lb = ob[34];
        float p0 = ob[35], p1 = ob[36], p2 = ob[37], p3 = ob[38];
        float c0 = ob[39], c1 = ob[40];
        #pragma unroll
        for (int r = 0; r < NR; ++r) {
            float t = fmaf(l0, xh[r][0], fmaf(l1, xh[r][1], fmaf(l2, xh[r][2], fmaf(l3, xh[r][3], lb))));
            t = fmaf(p0, vv[r][0], fmaf(p1, vv[r][1], fmaf(p2, vv[r][2], fmaf(p3, vv[r][3], t))));
            t = fmaf(c0, uu[r][0], fmaf(c1, uu[r][1], t));
            o[r] = LN2f * sp2(t);
        }
    }

    if (full) {
        *(float2*)(out + r0) = make_float2(o[0], o[1]);
    } else {
        #pragma unroll
        for (int r = 0; r < NR; ++r)
            if (r0 + r < n) out[r0 + r] = o[r];
    }
}

extern "C" void kernel_launch(void* const* d_in, const int* in_sizes, int n_in,
                              void* d_out, int out_size, void* d_ws, size_t ws_size,
                              hipStream_t stream) {
    const float* p[37];
    for (int i = 0; i < 37; ++i) p[i] = (const float*)d_in[i];
    float* wb = (float*)d_ws;   // 267 floats
    const int n = in_sizes[0] / 2;  // N rows (D=2)

    prep_kernel<<<dim3(1), dim3(256), 0, stream>>>(
        p[2],  p[3],  p[4],  p[5],  p[6],  p[7],
        p[8],  p[9],  p[10], p[11], p[12], p[13],
        p[14], p[15],
        p[16], p[17], p[18],
        p[19], p[20], p[21], p[22], p[23], p[24],
        p[25], p[26], p[27], p[28],
        p[29], p[30], p[31], p[32], p[33], p[34],
        p[35], p[36],
        wb);

    const int threads = 256;
    const int rows_per_block = threads * NR;
    const int blocks = (n + rows_per_block - 1) / rows_per_block;
    dissip_main<<<dim3(blocks), dim3(threads), 0, stream>>>(
        p[0], p[1], wb, (float*)d_out, n);
}

// Round 4
// 161.805 us; speedup vs baseline: 1.2037x; 1.1162x over previous
//
#include <hip/hip_runtime.h>

// DissipationNetwork: per-row tiny ICNN, N=2^21 rows, D=2, H=4. VALU-bound map.
//  1) prep_kernel: 35 blocks, one weight-segment each — folds PositiveLinear
//     reparam + log2-domain softplus constants into 267-float wb in d_ws.
//  2) dissip_main: 2 rows/thread packed into float2 lanes -> v_pk_fma_f32 etc.
//     softplus in log2 domain (raw v_exp_f32/v_log_f32, modifiers folded).
//
// log2-domain: activation a = ln2 * a_hat, a_hat = sp2(z_hat), z_hat = z*log2e.
// sp2(y) = max(y,0) + log2(1 + 2^-|y|). Scale factors telescope; absorbed into
// precomputed weights (input-side *log2e, product-path *ln2, output *ln2 once).

typedef float v2f __attribute__((ext_vector_type(2)));

#define NR 2
#define L2Ef 1.4426950408889634f
#define LN2f 0.6931471805599453f

__device__ __forceinline__ v2f vsplat(float s) { v2f r; r.x = s; r.y = s; return r; }
__device__ __forceinline__ v2f vfma(float w, v2f x, v2f a) {
    return __builtin_elementwise_fma(vsplat(w), x, a);   // -> v_pk_fma_f32
}
__device__ __forceinline__ v2f sp2v(v2f y) {
    v2f e, l;
    e.x = __builtin_amdgcn_exp2f(-fabsf(y.x));   // 2^-|y|
    e.y = __builtin_amdgcn_exp2f(-fabsf(y.y));
    l.x = __builtin_amdgcn_logf(1.0f + e.x);     // log2(1+e)
    l.y = __builtin_amdgcn_logf(1.0f + e.y);
    return __builtin_elementwise_max(y, vsplat(0.0f)) + l;
}
__device__ __forceinline__ float posw(float w) {
    // PositiveLinear reparam, EPS=1
    return (w >= 0.0f) ? (w + 0.36787944117144233f) : __expf(w - 1.0f);
}

// ---- transformed weight buffer layout (267 floats) ----
// stage1: [0]w_xl1*L2E(8) [8]b_xl1*L2E(4) [12]w_clin*L2E(8) [20]w_clinm(4)
//         [24]b_clinm(2) [26]w_xin*L2E(8) [34]b_xin*L2E(4)
// stage block (base B=38 / B=132, 94 floats):
//   B+0 w_cpm(16) B+16 b_cpm*L2E(4) B+20 w_clm*LN2(8) B+28 b_clm(2)
//   B+30 w_xl(16) B+46 b_xl*L2E(4)  B+50 LN2*posw(w_cp)(16) B+66 w_cl*L2E(8)
//   B+74 w_xp(16) B+90 b_xp*L2E(4)
// out: [226]w_cpom(16) [242]b_cpom*L2E(4) [246]w_clom*LN2(8) [254]b_clom(2)
//      [256]w_xlo(4) [260]b_xlo*L2E(1) [261]LN2*posw(w_cpo)(4) [265]w_clo*L2E(2)

__global__ __launch_bounds__(64)
void prep_kernel(
    const float* __restrict__ w_xin,  const float* __restrict__ b_xin,
    const float* __restrict__ w_xp1,  const float* __restrict__ b_xp1,
    const float* __restrict__ w_xp2,  const float* __restrict__ b_xp2,
    const float* __restrict__ w_xl1,  const float* __restrict__ b_xl1,
    const float* __restrict__ w_xl2,  const float* __restrict__ b_xl2,
    const float* __restrict__ w_xl3,  const float* __restrict__ b_xl3,
    const float* __restrict__ w_xlo,  const float* __restrict__ b_xlo,
    const float* __restrict__ w_cp1,  const float* __restrict__ w_cp2,
    const float* __restrict__ w_cpo,
    const float* __restrict__ w_cp1m, const float* __restrict__ b_cp1m,
    const float* __restrict__ w_cp2m, const float* __restrict__ b_cp2m,
    const float* __restrict__ w_cpom, const float* __restrict__ b_cpom,
    const float* __restrict__ w_clin, const float* __restrict__ w_cl1,
    const float* __restrict__ w_cl2,  const float* __restrict__ w_clo,
    const float* __restrict__ w_clinm,const float* __restrict__ b_clinm,
    const float* __restrict__ w_cl1m, const float* __restrict__ b_cl1m,
    const float* __restrict__ w_cl2m, const float* __restrict__ b_cl2m,
    const float* __restrict__ w_clom, const float* __restrict__ b_clom,
    float* __restrict__ wb)
{
    const int t = threadIdx.x;
#define SEG(i, dst, src, cnt, EXPR) \
    case i: if (t < (cnt)) { float s_ = (src)[t]; wb[(dst)+t] = (EXPR); } break;
    switch (blockIdx.x) {
    SEG(0,  0,   w_xl1,  8,  L2Ef*s_)
    SEG(1,  8,   b_xl1,  4,  L2Ef*s_)
    SEG(2,  12,  w_clin, 8,  L2Ef*s_)
    SEG(3,  20,  w_clinm,4,  s_)
    SEG(4,  24,  b_clinm,2,  s_)
    SEG(5,  26,  w_xin,  8,  L2Ef*s_)
    SEG(6,  34,  b_xin,  4,  L2Ef*s_)
    SEG(7,  38,  w_cp1m, 16, s_)
    SEG(8,  54,  b_cp1m, 4,  L2Ef*s_)
    SEG(9,  58,  w_cl1m, 8,  LN2f*s_)
    SEG(10, 66,  b_cl1m, 2,  s_)
    SEG(11, 68,  w_xl2,  16, s_)
    SEG(12, 84,  b_xl2,  4,  L2Ef*s_)
    SEG(13, 88,  w_cp1,  16, LN2f*posw(s_))
    SEG(14, 104, w_cl1,  8,  L2Ef*s_)
    SEG(15, 112, w_xp1,  16, s_)
    SEG(16, 128, b_xp1,  4,  L2Ef*s_)
    SEG(17, 132, w_cp2m, 16, s_)
    SEG(18, 148, b_cp2m, 4,  L2Ef*s_)
    SEG(19, 152, w_cl2m, 8,  LN2f*s_)
    SEG(20, 160, b_cl2m, 2,  s_)
    SEG(21, 162, w_xl3,  16, s_)
    SEG(22, 178, b_xl3,  4,  L2Ef*s_)
    SEG(23, 182, w_cp2,  16, LN2f*posw(s_))
    SEG(24, 198, w_cl2,  8,  L2Ef*s_)
    SEG(25, 206, w_xp2,  16, s_)
    SEG(26, 222, b_xp2,  4,  L2Ef*s_)
    SEG(27, 226, w_cpom, 16, s_)
    SEG(28, 242, b_cpom, 4,  L2Ef*s_)
    SEG(29, 246, w_clom, 8,  LN2f*s_)
    SEG(30, 254, b_clom, 2,  s_)
    SEG(31, 256, w_xlo,  4,  s_)
    SEG(32, 260, b_xlo,  1,  L2Ef*s_)
    SEG(33, 261, w_cpo,  4,  LN2f*posw(s_))
    SEG(34, 265, w_clo,  2,  L2Ef*s_)
    }
#undef SEG
}

__device__ __forceinline__ void mid_stage(const float* __restrict__ wb,
                                          v2f xs[4], v2f xh[4], const v2f XS0[2])
{
    // v[h] = xs[h] * sp2(w_cpm@xh + b_cpm)
    v2f v[4];
    #pragma unroll
    for (int h = 0; h < 4; ++h) {
        v2f t = vfma(wb[h*4+0], xh[0], vfma(wb[h*4+1], xh[1],
                vfma(wb[h*4+2], xh[2], vfma(wb[h*4+3], xh[3], vsplat(wb[16+h])))));
        v[h] = xs[h] * sp2v(t);
    }
    // u[d] = x0s[d] * (w_clm@xh + b_clm)
    v2f u[2];
    #pragma unroll
    for (int d = 0; d < 2; ++d) {
        v2f t = vfma(wb[20+d*4+0], xh[0], vfma(wb[20+d*4+1], xh[1],
                vfma(wb[20+d*4+2], xh[2], vfma(wb[20+d*4+3], xh[3], vsplat(wb[28+d])))));
        u[d] = XS0[d] * t;
    }
    // xs' = sp2(w_xl@xh + b_xl + P@v + w_cl@u);  xh' = sp2(w_xp@xh + b_xp)
    v2f ns[4], nh[4];
    #pragma unroll
    for (int h = 0; h < 4; ++h) {
        v2f t = vfma(wb[30+h*4+0], xh[0], vfma(wb[30+h*4+1], xh[1],
                vfma(wb[30+h*4+2], xh[2], vfma(wb[30+h*4+3], xh[3], vsplat(wb[46+h])))));
        t = vfma(wb[50+h*4+0], v[0], vfma(wb[50+h*4+1], v[1],
            vfma(wb[50+h*4+2], v[2], vfma(wb[50+h*4+3], v[3], t))));
        t = vfma(wb[66+h*2+0], u[0], vfma(wb[66+h*2+1], u[1], t));
        ns[h] = sp2v(t);
    }
    #pragma unroll
    for (int h = 0; h < 4; ++h) {
        v2f t = vfma(wb[74+h*4+0], xh[0], vfma(wb[74+h*4+1], xh[1],
                vfma(wb[74+h*4+2], xh[2], vfma(wb[74+h*4+3], xh[3], vsplat(wb[90+h])))));
        nh[h] = sp2v(t);
    }
    #pragma unroll
    for (int h = 0; h < 4; ++h) { xs[h] = ns[h]; xh[h] = nh[h]; }
}

__global__ __launch_bounds__(256, 4)
void dissip_main(const float* __restrict__ x, const float* __restrict__ xst,
                 const float* __restrict__ wb, float* __restrict__ out, int n)
{
    const int tid = blockIdx.x * blockDim.x + threadIdx.x;
    const int r0  = tid * NR;
    if (r0 >= n) return;
    const bool full = (r0 + NR <= n);

    // lane-in-register packing: v2f element 0 = row r0, element 1 = row r0+1
    v2f X0[2], XS0[2];
    if (full) {
        const float4 xa = *(const float4*)(x   + (size_t)r0 * 2);
        const float4 sa = *(const float4*)(xst + (size_t)r0 * 2);
        X0[0].x = xa.x;  X0[0].y = xa.z;  X0[1].x = xa.y;  X0[1].y = xa.w;
        XS0[0].x = sa.x; XS0[0].y = sa.z; XS0[1].x = sa.y; XS0[1].y = sa.w;
    } else {
        X0[0] = vsplat(0.0f); X0[1] = vsplat(0.0f);
        XS0[0] = vsplat(0.0f); XS0[1] = vsplat(0.0f);
        X0[0].x  = x[(size_t)r0*2];   X0[1].x  = x[(size_t)r0*2+1];
        XS0[0].x = xst[(size_t)r0*2]; XS0[1].x = xst[(size_t)r0*2+1];
    }

    v2f xs[4], xh[4];

    // ---- stage 1 ----
    v2f tcl[2];
    tcl[0] = XS0[0] * vfma(wb[20], X0[0], vfma(wb[21], X0[1], vsplat(wb[24])));
    tcl[1] = XS0[1] * vfma(wb[22], X0[0], vfma(wb[23], X0[1], vsplat(wb[25])));
    #pragma unroll
    for (int h = 0; h < 4; ++h) {
        v2f a = vfma(wb[h*2+0], X0[0], vfma(wb[h*2+1], X0[1], vsplat(wb[8+h])));
        a = vfma(wb[12+h*2+0], tcl[0], vfma(wb[12+h*2+1], tcl[1], a));
        xs[h] = sp2v(a);
    }
    #pragma unroll
    for (int h = 0; h < 4; ++h)
        xh[h] = sp2v(vfma(wb[26+h*2+0], X0[0], vfma(wb[26+h*2+1], X0[1], vsplat(wb[34+h]))));

    // ---- stages 2, 3 ----
    mid_stage(wb + 38,  xs, xh, XS0);
    mid_stage(wb + 132, xs, xh, XS0);

    // ---- output stage ----
    const float* ob = wb + 226;
    v2f vv[4];
    #pragma unroll
    for (int h = 0; h < 4; ++h) {
        v2f t = vfma(ob[h*4+0], xh[0], vfma(ob[h*4+1], xh[1],
                vfma(ob[h*4+2], xh[2], vfma(ob[h*4+3], xh[3], vsplat(ob[16+h])))));
        vv[h] = xs[h] * sp2v(t);
    }
    v2f uu[2];
    #pragma unroll
    for (int d = 0; d < 2; ++d) {
        v2f t = vfma(ob[20+d*4+0], xh[0], vfma(ob[20+d*4+1], xh[1],
                vfma(ob[20+d*4+2], xh[2], vfma(ob[20+d*4+3], xh[3], vsplat(ob[28+d])))));
        uu[d] = XS0[d] * t;
    }
    v2f t = vfma(ob[30], xh[0], vfma(ob[31], xh[1],
            vfma(ob[32], xh[2], vfma(ob[33], xh[3], vsplat(ob[34])))));
    t = vfma(ob[35], vv[0], vfma(ob[36], vv[1],
        vfma(ob[37], vv[2], vfma(ob[38], vv[3], t))));
    t = vfma(ob[39], uu[0], vfma(ob[40], uu[1], t));
    v2f o = vsplat(LN2f) * sp2v(t);

    if (full) {
        *(v2f*)(out + r0) = o;
    } else {
        out[r0] = o.x;
    }
}

extern "C" void kernel_launch(void* const* d_in, const int* in_sizes, int n_in,
                              void* d_out, int out_size, void* d_ws, size_t ws_size,
                              hipStream_t stream) {
    const float* p[37];
    for (int i = 0; i < 37; ++i) p[i] = (const float*)d_in[i];
    float* wb = (float*)d_ws;   // 267 floats
    const int n = in_sizes[0] / 2;  // N rows (D=2)

    prep_kernel<<<dim3(35), dim3(64), 0, stream>>>(
        p[2],  p[3],  p[4],  p[5],  p[6],  p[7],
        p[8],  p[9],  p[10], p[11], p[12], p[13],
        p[14], p[15],
        p[16], p[17], p[18],
        p[19], p[20], p[21], p[22], p[23], p[24],
        p[25], p[26], p[27], p[28],
        p[29], p[30], p[31], p[32], p[33], p[34],
        p[35], p[36],
        wb);

    const int threads = 256;
    const int rows_per_block = threads * NR;
    const int blocks = (n + rows_per_block - 1) / rows_per_block;
    dissip_main<<<dim3(blocks), dim3(threads), 0, stream>>>(
        p[0], p[1], wb, (float*)d_out, n);
}